// Round 9
// baseline (408.254 us; speedup 1.0000x reference)
//
#include <hip/hip_runtime.h>
#include <hip/hip_fp16.h>
#include <hip/hip_cooperative_groups.h>

namespace cg = cooperative_groups;

#define NN 50000
#define DD 128
#define NE 800000
#define BN_EPS 1e-5f
#define NBUCK 196           // ceil(NN/256): bucket = dst>>8, 256 nodes per bucket
#define TILE_A 4096         // edges per k_csr block (196*4096 >= 800000)

typedef _Float16 f16x8 __attribute__((ext_vector_type(8)));
typedef float f32x4 __attribute__((ext_vector_type(4)));

// ---------------- cooperative CSR build: zero + hist + scatter + sort ------------
// One kernel (196 blocks, trivially co-resident at 1 block/CU) replaces
// memset + binA1 + binA2 + binB.  grid.sync() replaces 3 dispatch boundaries.
// __threadfence() before each grid.sync for cross-XCD write visibility.
__global__ __launch_bounds__(256) void k_csr(const int* __restrict__ src,
                                             const int* __restrict__ dst,
                                             int* __restrict__ bucketCnt,
                                             int* __restrict__ bucketRes,
                                             unsigned* __restrict__ evS,
                                             unsigned* __restrict__ ev,
                                             int* __restrict__ rowp,
                                             float* __restrict__ dinv,
                                             int ne, int n) {
    cg::grid_group grid = cg::this_grid();
    __shared__ int sc[256];
    __shared__ int sExcl[256];
    __shared__ int hcnt[NBUCK];
    __shared__ int hbase[NBUCK];
    __shared__ int ncnt[256];
    __shared__ int ncur[256];
    int tid = threadIdx.x;
    int blk = blockIdx.x;

    // phase 0: zero bucketCnt(256)+bucketRes(256)+sums(8192)+Zb(64) = 8768 ints
    for (int i = blk * 256 + tid; i < 8768; i += NBUCK * 256) bucketCnt[i] = 0;
    __threadfence();
    grid.sync();

    // phase 1: per-block LDS histogram -> global bucketCnt
    for (int i = tid; i < NBUCK; i += 256) hcnt[i] = 0;
    __syncthreads();
    int base = blk * TILE_A;
    int lim = ne - base;
    if (lim > TILE_A) lim = TILE_A;
    for (int i = tid; i < lim; i += 256) atomicAdd(&hcnt[dst[base + i] >> 8], 1);
    __syncthreads();
    for (int b = tid; b < NBUCK; b += 256)
        if (hcnt[b]) atomicAdd(&bucketCnt[b], hcnt[b]);
    __threadfence();
    grid.sync();

    // phase 2: local scan of final bucketCnt, reserve runs, rank-scatter staging
    {
        int v = (tid < NBUCK) ? bucketCnt[tid] : 0;
        sc[tid] = v;
        __syncthreads();
        for (int off = 1; off < 256; off <<= 1) {
            int add = (tid >= off) ? sc[tid - off] : 0;
            __syncthreads();
            sc[tid] += add;
            __syncthreads();
        }
        sExcl[tid] = sc[tid] - v;
    }
    __syncthreads();
    for (int b = tid; b < NBUCK; b += 256) {
        hbase[b] = hcnt[b] ? (sExcl[b] + atomicAdd(&bucketRes[b], hcnt[b])) : 0;
        hcnt[b] = 0;
    }
    __syncthreads();
    for (int i = tid; i < lim; i += 256) {
        int d = dst[base + i];
        int s = src[base + i];
        int bk = d >> 8;
        int rank = atomicAdd(&hcnt[bk], 1);
        evS[hbase[bk] + rank] = (unsigned)s | ((unsigned)(d & 255) << 16);
    }
    __threadfence();
    grid.sync();

    // phase 3: per-bucket counting sort (block = bucket) -> ev, rowp, dinv
    int lo = sExcl[blk];
    int cnt_b = bucketCnt[blk];
    ncnt[tid] = 0;
    __syncthreads();
    for (int p = tid; p < cnt_b; p += 256)
        atomicAdd(&ncnt[evS[lo + p] >> 16], 1);
    __syncthreads();
    int nv = ncnt[tid];
    sc[tid] = nv;
    __syncthreads();
    for (int off = 1; off < 256; off <<= 1) {
        int add = (tid >= off) ? sc[tid - off] : 0;
        __syncthreads();
        sc[tid] += add;
        __syncthreads();
    }
    int nb = sc[tid] - nv;
    ncur[tid] = nb;
    int node = (blk << 8) + tid;
    if (node < n) {
        rowp[node] = lo + nb;
        dinv[node] = 1.0f / sqrtf((float)(nv + 1));
    }
    if (blk == NBUCK - 1 && tid == 0) rowp[n] = lo + cnt_b;
    __syncthreads();
    for (int p = tid; p < cnt_b; p += 256) {
        unsigned r = evS[lo + p];
        int ln = r >> 16;
        int rank = atomicAdd(&ncur[ln], 1);
        ev[lo + rank] = r & 0xFFFFu;
    }
}

// ---------------- GEMM: MFMA fp16, inline W conversion, fused BN prologue --------
#define GTILE 64
__global__ __launch_bounds__(256) void k_gemm(const float* __restrict__ A,
                                              const float* __restrict__ res,
                                              const float* __restrict__ sums,
                                              const float* __restrict__ gamma,
                                              const float* __restrict__ beta,
                                              float* __restrict__ Hout,
                                              const float* __restrict__ dscale,
                                              const float* __restrict__ W,
                                              __half* __restrict__ C, int n) {
    __shared__ __half sW[DD * DD];       // 32 KB fragment-linear (no swizzle)
    __shared__ __half sA[GTILE * DD];    // 16 KB fragment-linear (swizzled)
    __shared__ float s_scale[DD], s_shift[DD];
    int tid = threadIdx.x;
    int wave = tid >> 6;
    int lane = tid & 63;
    bool fused = (res != nullptr);

    {   // stage W: fp32 -> fp16 B-fragment layout, in-kernel
        for (int s = tid; s < DD * DD / 8; s += 256) {
            int l = s & 63;
            int ks = (s >> 6) & 3;
            int cb = s >> 8;
            int col = cb * 16 + (l & 15);
            int kbase = ks * 32 + (l >> 4) * 8;
            __align__(16) __half tmp[8];
            #pragma unroll
            for (int j = 0; j < 8; j++)
                tmp[j] = __float2half_rn(W[(kbase + j) * DD + col]);
            *(uint4*)(sW + s * 8) = *(uint4*)tmp;
        }
    }
    if (fused && tid < DD) {
        float ssum = 0.f, qsum = 0.f;
        #pragma unroll
        for (int b = 0; b < 16; b++) {
            ssum += sums[b * 256 + tid];
            qsum += sums[b * 256 + 128 + tid];
        }
        float inv_n = 1.0f / (float)n;
        float mean = ssum * inv_n;
        float var = qsum * inv_n - mean * mean;
        float sc = gamma[tid] * (1.0f / sqrtf(var + BN_EPS));
        s_scale[tid] = sc;
        s_shift[tid] = beta[tid] - mean * sc;
    }

    int ntiles = (n + GTILE - 1) / GTILE;
    for (int t = blockIdx.x; t < ntiles; t += gridDim.x) {
        int row0 = t * GTILE;
        __syncthreads();   // covers W/stats stage (1st iter) + prev-tile reads
        {   // stage A tile: (optional BN+ReLU+res) fp32 -> fp16 fragments, swizzled
            const float4* Av = (const float4*)(A + (size_t)row0 * DD);
            const float4* Rv = (const float4*)(res + (size_t)row0 * DD);
            float4* Hv = (float4*)(Hout + (size_t)row0 * DD);
            for (int i = tid; i < GTILE * DD / 4; i += 256) {
                int r = i >> 5;         // row in tile
                int kq = i & 31;        // k = 4*kq
                bool rowok = (row0 + r < n);
                float4 v = make_float4(0.f, 0.f, 0.f, 0.f);
                if (rowok) v = Av[i];
                if (fused) {
                    float4 rv = make_float4(0.f, 0.f, 0.f, 0.f);
                    if (rowok) rv = Rv[i];
                    int f4 = kq * 4;
                    v.x = fmaxf(v.x * s_scale[f4]     + s_shift[f4],     0.f) + rv.x;
                    v.y = fmaxf(v.y * s_scale[f4 + 1] + s_shift[f4 + 1], 0.f) + rv.y;
                    v.z = fmaxf(v.z * s_scale[f4 + 2] + s_shift[f4 + 2], 0.f) + rv.z;
                    v.w = fmaxf(v.w * s_scale[f4 + 3] + s_shift[f4 + 3], 0.f) + rv.w;
                    if (rowok) Hv[i] = v;
                }
                __half2 p0 = __floats2half2_rn(v.x, v.y);
                __half2 p1 = __floats2half2_rn(v.z, v.w);
                uint2 pk;
                pk.x = *(unsigned*)&p0;
                pk.y = *(unsigned*)&p1;
                int slot = ((r >> 4) * 4 + (kq >> 3)) * 64 +
                           (((kq >> 1) & 3) << 4) + (r & 15);
                int byte = slot * 16 + (kq & 1) * 8;
                byte ^= ((byte >> 9) & 7) << 4;
                *(uint2*)((char*)sA + byte) = pk;
            }
        }
        __syncthreads();

        f32x4 acc[8];
        #pragma unroll
        for (int cb = 0; cb < 8; cb++) acc[cb] = (f32x4)(0.0f);
        f16x8 af[4];
        #pragma unroll
        for (int ks = 0; ks < 4; ks++) {
            int rb = ((wave * 4 + ks) * 64 + lane) * 16;
            rb ^= ((rb >> 9) & 7) << 4;
            af[ks] = *(const f16x8*)((const char*)sA + rb);
        }
        #pragma unroll
        for (int cb = 0; cb < 8; cb++) {
            #pragma unroll
            for (int ks = 0; ks < 4; ks++) {
                f16x8 bf = *(const f16x8*)(sW + ((cb * 4 + ks) * 64 + lane) * 8);
                acc[cb] = __builtin_amdgcn_mfma_f32_16x16x32_f16(af[ks], bf,
                                                                 acc[cb], 0, 0, 0);
            }
        }

        // RACE FIX barrier: all waves' af ds_reads must retire before any wave
        // overwrites the staging buffer with its epilogue sC writes.
        __syncthreads();

        // per-row dinv scale for the fp16 gather table
        float dv[4];
        #pragma unroll
        for (int rr = 0; rr < 4; rr++) {
            int row = row0 + wave * 16 + (lane >> 4) * 4 + rr;
            dv[rr] = (row < n) ? dscale[row] : 1.f;
        }

        // epilogue: acc -> per-wave LDS region (col-xor spreads banks) -> coalesced
        __half* sC = sA + wave * (16 * DD);
        #pragma unroll
        for (int cb = 0; cb < 8; cb++) {
            int col = cb * 16 + (lane & 15);
            #pragma unroll
            for (int rr = 0; rr < 4; rr++) {
                int grow = (lane >> 4) * 4 + rr;
                sC[grow * DD + (col ^ ((grow & 3) << 4))] =
                    __float2half(acc[cb][rr] * dv[rr]);
            }
        }
        __syncthreads();
        #pragma unroll
        for (int i2 = 0; i2 < 4; i2++) {
            int o = (i2 * 64 + lane) * 8;   // half index in wave's 16x128 region
            int grow = o >> 7;
            int col0 = o & 127;
            int row = row0 + wave * 16 + grow;
            if (row < n) {
                uint4 val = *(uint4*)(sC + grow * DD + (col0 ^ ((grow & 3) << 4)));
                *(uint4*)(C + (size_t)row * DD + col0) = val;
            }
        }
    }
}

// ---------------- aggregation: 16 lanes/node, 4-deep pipelined gather ------------
#define ACC8(raw) { const __half2* hp_ = (const __half2*)&(raw);               \
    float2 c0_ = __half22float2(hp_[0]); float2 c1_ = __half22float2(hp_[1]);  \
    float2 c2_ = __half22float2(hp_[2]); float2 c3_ = __half22float2(hp_[3]);  \
    a[0] += c0_.x; a[1] += c0_.y; a[2] += c1_.x; a[3] += c1_.y;                \
    a[4] += c2_.x; a[5] += c2_.y; a[6] += c3_.x; a[7] += c3_.y; }

__global__ __launch_bounds__(256) void k_agg(const __half* __restrict__ h,
                                             const int* __restrict__ rowp,
                                             const unsigned* __restrict__ ev,
                                             const float* __restrict__ dinv,
                                             const float* __restrict__ bias,
                                             float* __restrict__ out,
                                             float* __restrict__ sums, int n) {
    int tid = threadIdx.x;
    int grp = tid >> 4;            // node within block 0..15
    int m = tid & 15;              // 16 B chunk within row
    int node = blockIdx.x * 16 + grp;
    bool activ = node < n;

    int beg = 0, end = 0;
    float di = 0.f;
    if (activ) { beg = rowp[node]; end = rowp[node + 1]; di = dinv[node]; }

    float sf[8] = {0.f, 0.f, 0.f, 0.f, 0.f, 0.f, 0.f, 0.f};
    float bf[8];
    {
        float4 b0 = *(const float4*)(bias + m * 8);
        float4 b1 = *(const float4*)(bias + m * 8 + 4);
        bf[0] = b0.x; bf[1] = b0.y; bf[2] = b0.z; bf[3] = b0.w;
        bf[4] = b1.x; bf[5] = b1.y; bf[6] = b1.z; bf[7] = b1.w;
        if (activ) {
            float4 raw = *(const float4*)(h + (size_t)node * DD + m * 8);
            const __half2* hp = (const __half2*)&raw;
            float2 s0 = __half22float2(hp[0]);
            float2 s1 = __half22float2(hp[1]);
            float2 s2 = __half22float2(hp[2]);
            float2 s3 = __half22float2(hp[3]);
            sf[0] = s0.x; sf[1] = s0.y; sf[2] = s1.x; sf[3] = s1.y;
            sf[4] = s2.x; sf[5] = s2.y; sf[6] = s3.x; sf[7] = s3.y;
        }
    }

    float a[8] = {0.f, 0.f, 0.f, 0.f, 0.f, 0.f, 0.f, 0.f};
    int e = beg;
    int cnt4 = (end - beg) >> 2;
    if (cnt4 > 0) {
        unsigned s0 = ev[e], s1 = ev[e + 1], s2 = ev[e + 2], s3 = ev[e + 3];
        float4 r0 = *(const float4*)(h + (size_t)s0 * DD + m * 8);
        float4 r1 = *(const float4*)(h + (size_t)s1 * DD + m * 8);
        float4 r2 = *(const float4*)(h + (size_t)s2 * DD + m * 8);
        float4 r3 = *(const float4*)(h + (size_t)s3 * DD + m * 8);
        for (int g = 1; g < cnt4; g++) {
            e += 4;
            unsigned t0 = ev[e], t1 = ev[e + 1], t2 = ev[e + 2], t3 = ev[e + 3];
            float4 q0 = *(const float4*)(h + (size_t)t0 * DD + m * 8);
            float4 q1 = *(const float4*)(h + (size_t)t1 * DD + m * 8);
            float4 q2 = *(const float4*)(h + (size_t)t2 * DD + m * 8);
            float4 q3 = *(const float4*)(h + (size_t)t3 * DD + m * 8);
            ACC8(r0); ACC8(r1); ACC8(r2); ACC8(r3);
            r0 = q0; r1 = q1; r2 = q2; r3 = q3;
        }
        ACC8(r0); ACC8(r1); ACC8(r2); ACC8(r3);
        e += 4;
    }
    for (; e < end; e++) {
        unsigned s = ev[e];
        float4 raw = *(const float4*)(h + (size_t)s * DD + m * 8);
        ACC8(raw);
    }

    float o[8];
    #pragma unroll
    for (int j = 0; j < 8; j++) o[j] = di * (a[j] + sf[j]) + bf[j];
    if (activ) {
        float* op = out + (size_t)node * DD + m * 8;
        *(float4*)op = make_float4(o[0], o[1], o[2], o[3]);
        *(float4*)(op + 4) = make_float4(o[4], o[5], o[6], o[7]);
    }

    __shared__ float rs[16][132];            // +4 pad breaks 128-stride conflicts
    #pragma unroll
    for (int j = 0; j < 8; j++) rs[grp][m * 8 + j] = activ ? o[j] : 0.f;
    __syncthreads();

    int bank = blockIdx.x & 15;
    if (tid < 128) {
        float s = 0.f;
        #pragma unroll
        for (int r2 = 0; r2 < 16; r2++) s += rs[r2][tid];
        atomicAdd(&sums[bank * 256 + tid], s);
    } else {
        int f = tid - 128;
        float q = 0.f;
        #pragma unroll
        for (int r2 = 0; r2 < 16; r2++) { float v = rs[r2][f]; q += v * v; }
        atomicAdd(&sums[bank * 256 + 128 + f], q);
    }
}

// ---------------- BN apply + ReLU + residual + fused attention score (layer 2) ----
__global__ __launch_bounds__(256) void k_bn(const float* __restrict__ X,
                                            const float* __restrict__ res,
                                            const float* __restrict__ sums,
                                            const float* __restrict__ gamma,
                                            const float* __restrict__ beta,
                                            const float* __restrict__ Wa,
                                            const float* __restrict__ ba,
                                            float* __restrict__ out,
                                            float* __restrict__ evec,
                                            float* __restrict__ Zb, int n) {
    __shared__ float s_scale[128], s_shift[128];
    if (threadIdx.x < 128) {
        int ff = threadIdx.x;
        float ssum = 0.f, qsum = 0.f;
        #pragma unroll
        for (int b = 0; b < 16; b++) {
            ssum += sums[b * 256 + ff];
            qsum += sums[b * 256 + 128 + ff];
        }
        float inv_n = 1.0f / (float)n;
        float mean = ssum * inv_n;
        float var = qsum * inv_n - mean * mean;
        float sc = gamma[ff] * (1.0f / sqrtf(var + BN_EPS));
        s_scale[ff] = sc;
        s_shift[ff] = beta[ff] - mean * sc;
    }
    __syncthreads();
    int idx = blockIdx.x * 256 + threadIdx.x;
    int total = n * (DD / 4);
    int f = (threadIdx.x & 31) * 4;
    float o[4] = {0.f, 0.f, 0.f, 0.f};
    if (idx < total) {
        float4 v = ((const float4*)X)[idx];
        float4 rv = ((const float4*)res)[idx];
        float vi[4] = {v.x, v.y, v.z, v.w};
        float ri[4] = {rv.x, rv.y, rv.z, rv.w};
        #pragma unroll
        for (int j = 0; j < 4; j++) {
            float x = vi[j] * s_scale[f + j] + s_shift[f + j];
            x = fmaxf(x, 0.f);
            o[j] = x + ri[j];
        }
        ((float4*)out)[idx] = make_float4(o[0], o[1], o[2], o[3]);
    }
    if (Wa != nullptr) {
        float t = 0.f;
        if (idx < total) {
            float4 wv = *(const float4*)(Wa + f);
            t = o[0] * wv.x + o[1] * wv.y + o[2] * wv.z + o[3] * wv.w;
        }
        #pragma unroll
        for (int m = 16; m >= 1; m >>= 1) t += __shfl_xor(t, m);
        __shared__ float part[8];
        if ((threadIdx.x & 31) == 0) {
            float ev = 0.f;
            if (idx < total) {
                ev = expf(tanhf(t + ba[0]));
                evec[idx >> 5] = ev;
            }
            part[threadIdx.x >> 5] = ev;
        }
        __syncthreads();
        if (threadIdx.x == 0) {
            float z = part[0] + part[1] + part[2] + part[3] +
                      part[4] + part[5] + part[6] + part[7];
            atomicAdd(&Zb[blockIdx.x & 63], z);
        }
    }
}

// ---------------- final: out = h * e / Z (Z from 64 banks) ----------------
__global__ __launch_bounds__(256) void k_out(const float* __restrict__ H,
                                             const float* __restrict__ evec,
                                             const float* __restrict__ Zb,
                                             float* __restrict__ out, int n) {
    __shared__ float sZ;
    if (threadIdx.x == 0) {
        float z = 0.f;
        #pragma unroll
        for (int i = 0; i < 64; i++) z += Zb[i];
        sZ = z;
    }
    __syncthreads();
    int idx = blockIdx.x * blockDim.x + threadIdx.x;
    int total = n * (DD / 4);
    if (idx >= total) return;
    int node = idx >> 5;
    float s = evec[node] / sZ;
    float4 h = ((const float4*)H)[idx];
    ((float4*)out)[idx] = make_float4(h.x * s, h.y * s, h.z * s, h.w * s);
}

extern "C" void kernel_launch(void* const* d_in, const int* in_sizes, int n_in,
                              void* d_out, int out_size, void* d_ws, size_t ws_size,
                              hipStream_t stream) {
    const float* x   = (const float*)d_in[0];
    const int* eidx  = (const int*)d_in[1];
    const float* W1  = (const float*)d_in[2];
    const float* b1  = (const float*)d_in[3];
    const float* g1  = (const float*)d_in[4];
    const float* be1 = (const float*)d_in[5];
    const float* W2  = (const float*)d_in[6];
    const float* b2  = (const float*)d_in[7];
    const float* g2  = (const float*)d_in[8];
    const float* be2 = (const float*)d_in[9];
    const float* Wa  = (const float*)d_in[10];
    const float* ba  = (const float*)d_in[11];
    float* out = (float*)d_out;

    const int* srcp = eidx;
    const int* dstp = eidx + NE;

    float* bufA = (float*)d_ws;              // N*D region; fp16 gather table
    float* bufB = bufA + (size_t)NN * DD;    // N*D (staging evS / agg out)
    float* bufC = bufB + (size_t)NN * DD;    // N*D (h1)
    unsigned* ev = (unsigned*)(bufC + (size_t)NN * DD);   // NE 4B records (src)
    float* dinv = (float*)(ev + NE);         // NN
    float* evec = dinv + NN;                 // NN
    // zeroed in k_csr phase 0 (contiguous 8768 ints from bucketCnt):
    int* bucketCnt = (int*)(evec + NN);      // 256 (NBUCK used)
    int* bucketRes = bucketCnt + 256;        // 256
    float* sums = (float*)(bucketRes + 256); // 2 layers x 16 banks x 256 = 8192
    float* Zb   = sums + 8192;               // 64 banks
    int* rowp   = (int*)(Zb + 64);           // NN+1 (pad 64)

    __half* hH  = (__half*)bufA;             // fp16 gather table, 12.8 MB
    unsigned* evS = (unsigned*)bufB;         // staged 4B records, 3.2 MB (aliased)

    float* sumsL1 = sums;
    float* sumsL2 = sums + 4096;

    int ne_c = NE, n_c = NN;

    // ---- CSR build: ONE cooperative kernel (196 blocks, 1/CU — safe) ----
    {
        void* args[] = {(void*)&srcp, (void*)&dstp, (void*)&bucketCnt,
                        (void*)&bucketRes, (void*)&evS, (void*)&ev,
                        (void*)&rowp, (void*)&dinv, (void*)&ne_c, (void*)&n_c};
        hipLaunchCooperativeKernel((const void*)k_csr, dim3(NBUCK), dim3(256),
                                   args, 0, stream);
    }

    int gemm_grid = (NN + GTILE - 1) / GTILE;        // 782
    int agg_grid  = (NN + 15) / 16;                  // 3125
    int ew_grid   = (NN * (DD / 4) + 255) / 256;     // 6250

    // ---- layer 1 (GEMM from x; table scaled by dinv; W converted in-kernel) ----
    k_gemm<<<gemm_grid, 256, 0, stream>>>(x, nullptr, nullptr, nullptr, nullptr,
                                          nullptr, dinv, W1, hH, NN);
    k_agg<<<agg_grid, 256, 0, stream>>>(hH, rowp, ev, dinv, b1, bufB, sumsL1, NN);

    // ---- layer 2 (BN1+ReLU+residual fused into GEMM2 staging; h1 -> bufC) ----
    k_gemm<<<gemm_grid, 256, 0, stream>>>(bufB, x, sumsL1, g1, be1, bufC,
                                          dinv, W2, hH, NN);
    k_agg<<<agg_grid, 256, 0, stream>>>(hH, rowp, ev, dinv, b2, bufB, sumsL2, NN);
    k_bn<<<ew_grid, 256, 0, stream>>>(bufB, bufC, sumsL2, g2, be2, Wa, ba,
                                      bufC, evec, Zb, NN);   // in-place res ok

    // ---- output ----
    k_out<<<ew_grid, 256, 0, stream>>>(bufC, evec, Zb, out, NN);
}

// Round 10
// 268.484 us; speedup vs baseline: 1.5206x; 1.5206x over previous
//
#include <hip/hip_runtime.h>
#include <hip/hip_fp16.h>

#define NN 50000
#define DD 128
#define NE 800000
#define BN_EPS 1e-5f
#define NBUCK 196           // ceil(NN/256): bucket = dst>>8, 256 nodes per bucket
#define TILE_A 4096         // edges per k_binA block
#define BCAP 5120           // fixed staging capacity per bucket (mean 4096, 16 sigma)

typedef _Float16 f16x8 __attribute__((ext_vector_type(8)));
typedef float f32x4 __attribute__((ext_vector_type(4)));

// ---------------- phase A: bucket scatter into FIXED-CAPACITY staging ------------
// Fixed per-bucket segments (bk*BCAP) remove the need for a global histogram
// pass (k_binA1 eliminated).  Per-block LDS hist -> one bucketCur atomic per
// (block,bucket) reserves a ~21-record run -> rank-scatter 4 B records.
__global__ __launch_bounds__(256) void k_binA(const int* __restrict__ src,
                                              const int* __restrict__ dst,
                                              int* __restrict__ bucketCur,
                                              unsigned* __restrict__ evS, int ne) {
    __shared__ int hcnt[NBUCK];
    __shared__ int hbase[NBUCK];
    int tid = threadIdx.x;
    for (int i = tid; i < NBUCK; i += 256) hcnt[i] = 0;
    __syncthreads();
    int base = blockIdx.x * TILE_A;
    int lim = ne - base;
    if (lim > TILE_A) lim = TILE_A;
    for (int i = tid; i < lim; i += 256) atomicAdd(&hcnt[dst[base + i] >> 8], 1);
    __syncthreads();
    for (int b = tid; b < NBUCK; b += 256) {
        hbase[b] = hcnt[b] ? (b * BCAP + atomicAdd(&bucketCur[b], hcnt[b])) : 0;
        hcnt[b] = 0;
    }
    __syncthreads();
    for (int i = tid; i < lim; i += 256) {
        int d = dst[base + i];
        int s = src[base + i];
        int bk = d >> 8;
        int rank = atomicAdd(&hcnt[bk], 1);
        evS[hbase[bk] + rank] = (unsigned)s | ((unsigned)(d & 255) << 16);
    }
}

// ---------------- phase B: per-bucket counting sort -> ev, rowp, dinv ------------
// One block per bucket.  bucketCur holds final per-bucket counts; the 196-entry
// exclusive scan (in-block, cheap) gives the true CSR base.  Produces the
// per-node CSR (rowp/dinv) as a byproduct of the 256-bin sort.
__global__ __launch_bounds__(256) void k_binB(const unsigned* __restrict__ evS,
                                              const int* __restrict__ bucketCur,
                                              unsigned* __restrict__ ev,
                                              int* __restrict__ rowp,
                                              float* __restrict__ dinv, int n) {
    __shared__ int sc[256];
    __shared__ int ncnt[256];
    __shared__ int ncur[256];
    int tid = threadIdx.x;
    int b = blockIdx.x;

    int v = (tid < NBUCK) ? bucketCur[tid] : 0;
    sc[tid] = v;
    __syncthreads();
    for (int off = 1; off < 256; off <<= 1) {
        int add = (tid >= off) ? sc[tid - off] : 0;
        __syncthreads();
        sc[tid] += add;
        __syncthreads();
    }
    int lo = sc[b] - ((b < NBUCK) ? bucketCur[b] : 0);   // exclusive base
    int cnt_b = bucketCur[b];
    int seg = b * BCAP;

    ncnt[tid] = 0;
    __syncthreads();
    for (int p = tid; p < cnt_b; p += 256)
        atomicAdd(&ncnt[evS[seg + p] >> 16], 1);
    __syncthreads();
    int nv = ncnt[tid];
    sc[tid] = nv;
    __syncthreads();
    for (int off = 1; off < 256; off <<= 1) {
        int add = (tid >= off) ? sc[tid - off] : 0;
        __syncthreads();
        sc[tid] += add;
        __syncthreads();
    }
    int nb = sc[tid] - nv;
    ncur[tid] = nb;
    int node = (b << 8) + tid;
    if (node < n) {
        rowp[node] = lo + nb;
        dinv[node] = 1.0f / sqrtf((float)(nv + 1));
    }
    if (b == NBUCK - 1 && tid == 0) rowp[n] = lo + cnt_b;
    __syncthreads();
    for (int p = tid; p < cnt_b; p += 256) {
        unsigned r = evS[seg + p];
        int ln = r >> 16;
        int rank = atomicAdd(&ncur[ln], 1);
        ev[lo + rank] = r & 0xFFFFu;
    }
}

// ---------------- GEMM: MFMA fp16, inline W conversion, fused BN prologue --------
#define GTILE 64
__global__ __launch_bounds__(256) void k_gemm(const float* __restrict__ A,
                                              const float* __restrict__ res,
                                              const float* __restrict__ sums,
                                              const float* __restrict__ gamma,
                                              const float* __restrict__ beta,
                                              float* __restrict__ Hout,
                                              const float* __restrict__ dscale,
                                              const float* __restrict__ W,
                                              __half* __restrict__ C, int n) {
    __shared__ __half sW[DD * DD];       // 32 KB fragment-linear (no swizzle)
    __shared__ __half sA[GTILE * DD];    // 16 KB fragment-linear (swizzled)
    __shared__ float s_scale[DD], s_shift[DD];
    int tid = threadIdx.x;
    int wave = tid >> 6;
    int lane = tid & 63;
    bool fused = (res != nullptr);

    {   // stage W: fp32 -> fp16 B-fragment layout, in-kernel
        for (int s = tid; s < DD * DD / 8; s += 256) {
            int l = s & 63;
            int ks = (s >> 6) & 3;
            int cb = s >> 8;
            int col = cb * 16 + (l & 15);
            int kbase = ks * 32 + (l >> 4) * 8;
            __align__(16) __half tmp[8];
            #pragma unroll
            for (int j = 0; j < 8; j++)
                tmp[j] = __float2half_rn(W[(kbase + j) * DD + col]);
            *(uint4*)(sW + s * 8) = *(uint4*)tmp;
        }
    }
    if (fused && tid < DD) {
        float ssum = 0.f, qsum = 0.f;
        #pragma unroll
        for (int b = 0; b < 16; b++) {
            ssum += sums[b * 256 + tid];
            qsum += sums[b * 256 + 128 + tid];
        }
        float inv_n = 1.0f / (float)n;
        float mean = ssum * inv_n;
        float var = qsum * inv_n - mean * mean;
        float sc = gamma[tid] * (1.0f / sqrtf(var + BN_EPS));
        s_scale[tid] = sc;
        s_shift[tid] = beta[tid] - mean * sc;
    }

    int ntiles = (n + GTILE - 1) / GTILE;
    for (int t = blockIdx.x; t < ntiles; t += gridDim.x) {
        int row0 = t * GTILE;
        __syncthreads();   // covers W/stats stage (1st iter) + prev-tile reads
        {   // stage A tile: (optional BN+ReLU+res) fp32 -> fp16 fragments, swizzled
            const float4* Av = (const float4*)(A + (size_t)row0 * DD);
            const float4* Rv = (const float4*)(res + (size_t)row0 * DD);
            float4* Hv = (float4*)(Hout + (size_t)row0 * DD);
            for (int i = tid; i < GTILE * DD / 4; i += 256) {
                int r = i >> 5;         // row in tile
                int kq = i & 31;        // k = 4*kq
                bool rowok = (row0 + r < n);
                float4 v = make_float4(0.f, 0.f, 0.f, 0.f);
                if (rowok) v = Av[i];
                if (fused) {
                    float4 rv = make_float4(0.f, 0.f, 0.f, 0.f);
                    if (rowok) rv = Rv[i];
                    int f4 = kq * 4;
                    v.x = fmaxf(v.x * s_scale[f4]     + s_shift[f4],     0.f) + rv.x;
                    v.y = fmaxf(v.y * s_scale[f4 + 1] + s_shift[f4 + 1], 0.f) + rv.y;
                    v.z = fmaxf(v.z * s_scale[f4 + 2] + s_shift[f4 + 2], 0.f) + rv.z;
                    v.w = fmaxf(v.w * s_scale[f4 + 3] + s_shift[f4 + 3], 0.f) + rv.w;
                    if (rowok) Hv[i] = v;
                }
                __half2 p0 = __floats2half2_rn(v.x, v.y);
                __half2 p1 = __floats2half2_rn(v.z, v.w);
                uint2 pk;
                pk.x = *(unsigned*)&p0;
                pk.y = *(unsigned*)&p1;
                int slot = ((r >> 4) * 4 + (kq >> 3)) * 64 +
                           (((kq >> 1) & 3) << 4) + (r & 15);
                int byte = slot * 16 + (kq & 1) * 8;
                byte ^= ((byte >> 9) & 7) << 4;
                *(uint2*)((char*)sA + byte) = pk;
            }
        }
        __syncthreads();

        f32x4 acc[8];
        #pragma unroll
        for (int cb = 0; cb < 8; cb++) acc[cb] = (f32x4)(0.0f);
        f16x8 af[4];
        #pragma unroll
        for (int ks = 0; ks < 4; ks++) {
            int rb = ((wave * 4 + ks) * 64 + lane) * 16;
            rb ^= ((rb >> 9) & 7) << 4;
            af[ks] = *(const f16x8*)((const char*)sA + rb);
        }
        #pragma unroll
        for (int cb = 0; cb < 8; cb++) {
            #pragma unroll
            for (int ks = 0; ks < 4; ks++) {
                f16x8 bf = *(const f16x8*)(sW + ((cb * 4 + ks) * 64 + lane) * 8);
                acc[cb] = __builtin_amdgcn_mfma_f32_16x16x32_f16(af[ks], bf,
                                                                 acc[cb], 0, 0, 0);
            }
        }

        // RACE FIX barrier: all waves' af ds_reads must retire before any wave
        // overwrites the staging buffer with its epilogue sC writes.
        __syncthreads();

        // per-row dinv scale for the fp16 gather table
        float dv[4];
        #pragma unroll
        for (int rr = 0; rr < 4; rr++) {
            int row = row0 + wave * 16 + (lane >> 4) * 4 + rr;
            dv[rr] = (row < n) ? dscale[row] : 1.f;
        }

        // epilogue: acc -> per-wave LDS region (col-xor spreads banks) -> coalesced
        __half* sC = sA + wave * (16 * DD);
        #pragma unroll
        for (int cb = 0; cb < 8; cb++) {
            int col = cb * 16 + (lane & 15);
            #pragma unroll
            for (int rr = 0; rr < 4; rr++) {
                int grow = (lane >> 4) * 4 + rr;
                sC[grow * DD + (col ^ ((grow & 3) << 4))] =
                    __float2half(acc[cb][rr] * dv[rr]);
            }
        }
        __syncthreads();
        #pragma unroll
        for (int i2 = 0; i2 < 4; i2++) {
            int o = (i2 * 64 + lane) * 8;   // half index in wave's 16x128 region
            int grow = o >> 7;
            int col0 = o & 127;
            int row = row0 + wave * 16 + grow;
            if (row < n) {
                uint4 val = *(uint4*)(sC + grow * DD + (col0 ^ ((grow & 3) << 4)));
                *(uint4*)(C + (size_t)row * DD + col0) = val;
            }
        }
    }
}

// ---------------- aggregation: 16 lanes/node, 4-deep pipelined gather ------------
#define ACC8(raw) { const __half2* hp_ = (const __half2*)&(raw);               \
    float2 c0_ = __half22float2(hp_[0]); float2 c1_ = __half22float2(hp_[1]);  \
    float2 c2_ = __half22float2(hp_[2]); float2 c3_ = __half22float2(hp_[3]);  \
    a[0] += c0_.x; a[1] += c0_.y; a[2] += c1_.x; a[3] += c1_.y;                \
    a[4] += c2_.x; a[5] += c2_.y; a[6] += c3_.x; a[7] += c3_.y; }

__global__ __launch_bounds__(256) void k_agg(const __half* __restrict__ h,
                                             const int* __restrict__ rowp,
                                             const unsigned* __restrict__ ev,
                                             const float* __restrict__ dinv,
                                             const float* __restrict__ bias,
                                             float* __restrict__ out,
                                             float* __restrict__ sums, int n) {
    int tid = threadIdx.x;
    int grp = tid >> 4;            // node within block 0..15
    int m = tid & 15;              // 16 B chunk within row
    int node = blockIdx.x * 16 + grp;
    bool activ = node < n;

    int beg = 0, end = 0;
    float di = 0.f;
    if (activ) { beg = rowp[node]; end = rowp[node + 1]; di = dinv[node]; }

    float sf[8] = {0.f, 0.f, 0.f, 0.f, 0.f, 0.f, 0.f, 0.f};
    float bf[8];
    {
        float4 b0 = *(const float4*)(bias + m * 8);
        float4 b1 = *(const float4*)(bias + m * 8 + 4);
        bf[0] = b0.x; bf[1] = b0.y; bf[2] = b0.z; bf[3] = b0.w;
        bf[4] = b1.x; bf[5] = b1.y; bf[6] = b1.z; bf[7] = b1.w;
        if (activ) {
            float4 raw = *(const float4*)(h + (size_t)node * DD + m * 8);
            const __half2* hp = (const __half2*)&raw;
            float2 s0 = __half22float2(hp[0]);
            float2 s1 = __half22float2(hp[1]);
            float2 s2 = __half22float2(hp[2]);
            float2 s3 = __half22float2(hp[3]);
            sf[0] = s0.x; sf[1] = s0.y; sf[2] = s1.x; sf[3] = s1.y;
            sf[4] = s2.x; sf[5] = s2.y; sf[6] = s3.x; sf[7] = s3.y;
        }
    }

    float a[8] = {0.f, 0.f, 0.f, 0.f, 0.f, 0.f, 0.f, 0.f};
    int e = beg;
    int cnt4 = (end - beg) >> 2;
    if (cnt4 > 0) {
        unsigned s0 = ev[e], s1 = ev[e + 1], s2 = ev[e + 2], s3 = ev[e + 3];
        float4 r0 = *(const float4*)(h + (size_t)s0 * DD + m * 8);
        float4 r1 = *(const float4*)(h + (size_t)s1 * DD + m * 8);
        float4 r2 = *(const float4*)(h + (size_t)s2 * DD + m * 8);
        float4 r3 = *(const float4*)(h + (size_t)s3 * DD + m * 8);
        for (int g = 1; g < cnt4; g++) {
            e += 4;
            unsigned t0 = ev[e], t1 = ev[e + 1], t2 = ev[e + 2], t3 = ev[e + 3];
            float4 q0 = *(const float4*)(h + (size_t)t0 * DD + m * 8);
            float4 q1 = *(const float4*)(h + (size_t)t1 * DD + m * 8);
            float4 q2 = *(const float4*)(h + (size_t)t2 * DD + m * 8);
            float4 q3 = *(const float4*)(h + (size_t)t3 * DD + m * 8);
            ACC8(r0); ACC8(r1); ACC8(r2); ACC8(r3);
            r0 = q0; r1 = q1; r2 = q2; r3 = q3;
        }
        ACC8(r0); ACC8(r1); ACC8(r2); ACC8(r3);
        e += 4;
    }
    for (; e < end; e++) {
        unsigned s = ev[e];
        float4 raw = *(const float4*)(h + (size_t)s * DD + m * 8);
        ACC8(raw);
    }

    float o[8];
    #pragma unroll
    for (int j = 0; j < 8; j++) o[j] = di * (a[j] + sf[j]) + bf[j];
    if (activ) {
        float* op = out + (size_t)node * DD + m * 8;
        *(float4*)op = make_float4(o[0], o[1], o[2], o[3]);
        *(float4*)(op + 4) = make_float4(o[4], o[5], o[6], o[7]);
    }

    __shared__ float rs[16][132];            // +4 pad breaks 128-stride conflicts
    #pragma unroll
    for (int j = 0; j < 8; j++) rs[grp][m * 8 + j] = activ ? o[j] : 0.f;
    __syncthreads();

    int bank = blockIdx.x & 15;
    if (tid < 128) {
        float s = 0.f;
        #pragma unroll
        for (int r2 = 0; r2 < 16; r2++) s += rs[r2][tid];
        atomicAdd(&sums[bank * 256 + tid], s);
    } else {
        int f = tid - 128;
        float q = 0.f;
        #pragma unroll
        for (int r2 = 0; r2 < 16; r2++) { float v = rs[r2][f]; q += v * v; }
        atomicAdd(&sums[bank * 256 + 128 + f], q);
    }
}

// ---------------- BN apply + ReLU + residual + fused attention score (layer 2) ----
__global__ __launch_bounds__(256) void k_bn(const float* __restrict__ X,
                                            const float* __restrict__ res,
                                            const float* __restrict__ sums,
                                            const float* __restrict__ gamma,
                                            const float* __restrict__ beta,
                                            const float* __restrict__ Wa,
                                            const float* __restrict__ ba,
                                            float* __restrict__ out,
                                            float* __restrict__ evec,
                                            float* __restrict__ Zb, int n) {
    __shared__ float s_scale[128], s_shift[128];
    if (threadIdx.x < 128) {
        int ff = threadIdx.x;
        float ssum = 0.f, qsum = 0.f;
        #pragma unroll
        for (int b = 0; b < 16; b++) {
            ssum += sums[b * 256 + ff];
            qsum += sums[b * 256 + 128 + ff];
        }
        float inv_n = 1.0f / (float)n;
        float mean = ssum * inv_n;
        float var = qsum * inv_n - mean * mean;
        float sc = gamma[ff] * (1.0f / sqrtf(var + BN_EPS));
        s_scale[ff] = sc;
        s_shift[ff] = beta[ff] - mean * sc;
    }
    __syncthreads();
    int idx = blockIdx.x * 256 + threadIdx.x;
    int total = n * (DD / 4);
    int f = (threadIdx.x & 31) * 4;
    float o[4] = {0.f, 0.f, 0.f, 0.f};
    if (idx < total) {
        float4 v = ((const float4*)X)[idx];
        float4 rv = ((const float4*)res)[idx];
        float vi[4] = {v.x, v.y, v.z, v.w};
        float ri[4] = {rv.x, rv.y, rv.z, rv.w};
        #pragma unroll
        for (int j = 0; j < 4; j++) {
            float x = vi[j] * s_scale[f + j] + s_shift[f + j];
            x = fmaxf(x, 0.f);
            o[j] = x + ri[j];
        }
        ((float4*)out)[idx] = make_float4(o[0], o[1], o[2], o[3]);
    }
    if (Wa != nullptr) {
        float t = 0.f;
        if (idx < total) {
            float4 wv = *(const float4*)(Wa + f);
            t = o[0] * wv.x + o[1] * wv.y + o[2] * wv.z + o[3] * wv.w;
        }
        #pragma unroll
        for (int m = 16; m >= 1; m >>= 1) t += __shfl_xor(t, m);
        __shared__ float part[8];
        if ((threadIdx.x & 31) == 0) {
            float ev = 0.f;
            if (idx < total) {
                ev = expf(tanhf(t + ba[0]));
                evec[idx >> 5] = ev;
            }
            part[threadIdx.x >> 5] = ev;
        }
        __syncthreads();
        if (threadIdx.x == 0) {
            float z = part[0] + part[1] + part[2] + part[3] +
                      part[4] + part[5] + part[6] + part[7];
            atomicAdd(&Zb[blockIdx.x & 63], z);
        }
    }
}

// ---------------- final: out = h * e / Z (Z from 64 banks) ----------------
__global__ __launch_bounds__(256) void k_out(const float* __restrict__ H,
                                             const float* __restrict__ evec,
                                             const float* __restrict__ Zb,
                                             float* __restrict__ out, int n) {
    __shared__ float sZ;
    if (threadIdx.x == 0) {
        float z = 0.f;
        #pragma unroll
        for (int i = 0; i < 64; i++) z += Zb[i];
        sZ = z;
    }
    __syncthreads();
    int idx = blockIdx.x * blockDim.x + threadIdx.x;
    int total = n * (DD / 4);
    if (idx >= total) return;
    int node = idx >> 5;
    float s = evec[node] / sZ;
    float4 h = ((const float4*)H)[idx];
    ((float4*)out)[idx] = make_float4(h.x * s, h.y * s, h.z * s, h.w * s);
}

extern "C" void kernel_launch(void* const* d_in, const int* in_sizes, int n_in,
                              void* d_out, int out_size, void* d_ws, size_t ws_size,
                              hipStream_t stream) {
    const float* x   = (const float*)d_in[0];
    const int* eidx  = (const int*)d_in[1];
    const float* W1  = (const float*)d_in[2];
    const float* b1  = (const float*)d_in[3];
    const float* g1  = (const float*)d_in[4];
    const float* be1 = (const float*)d_in[5];
    const float* W2  = (const float*)d_in[6];
    const float* b2  = (const float*)d_in[7];
    const float* g2  = (const float*)d_in[8];
    const float* be2 = (const float*)d_in[9];
    const float* Wa  = (const float*)d_in[10];
    const float* ba  = (const float*)d_in[11];
    float* out = (float*)d_out;

    const int* srcp = eidx;
    const int* dstp = eidx + NE;

    float* bufA = (float*)d_ws;              // N*D region; fp16 gather table
    float* bufB = bufA + (size_t)NN * DD;    // N*D (staging evS / agg out)
    float* bufC = bufB + (size_t)NN * DD;    // N*D (h1)
    unsigned* ev = (unsigned*)(bufC + (size_t)NN * DD);   // NE 4B records (src)
    float* dinv = (float*)(ev + NE);         // NN
    float* evec = dinv + NN;                 // NN
    // zeroed region (one memset): bucketCur(256) | sums(8192) | Zb(64)
    int* bucketCur = (int*)(evec + NN);      // 256 (NBUCK used)
    float* sums = (float*)(bucketCur + 256); // 2 layers x 16 banks x 256 = 8192
    float* Zb   = sums + 8192;               // 64 banks
    int* rowp   = (int*)(Zb + 64);           // NN+1 (pad 64)

    __half* hH  = (__half*)bufA;             // fp16 gather table, 12.8 MB
    unsigned* evS = (unsigned*)bufB;         // staged: NBUCK*BCAP*4B = 4.0 MB

    float* sumsL1 = sums;
    float* sumsL2 = sums + 4096;

    // ---- CSR build: 1 memset + 2 kernels (binA1 eliminated via fixed-cap) ----
    hipMemsetAsync(bucketCur, 0, (size_t)(256 + 8192 + 64) * sizeof(int), stream);
    const int nA = (NE + TILE_A - 1) / TILE_A;       // 196
    k_binA<<<nA, 256, 0, stream>>>(srcp, dstp, bucketCur, evS, NE);
    k_binB<<<NBUCK, 256, 0, stream>>>(evS, bucketCur, ev, rowp, dinv, NN);

    int gemm_grid = (NN + GTILE - 1) / GTILE;        // 782
    int agg_grid  = (NN + 15) / 16;                  // 3125
    int ew_grid   = (NN * (DD / 4) + 255) / 256;     // 6250

    // ---- layer 1 (GEMM from x; table scaled by dinv; W converted in-kernel) ----
    k_gemm<<<gemm_grid, 256, 0, stream>>>(x, nullptr, nullptr, nullptr, nullptr,
                                          nullptr, dinv, W1, hH, NN);
    k_agg<<<agg_grid, 256, 0, stream>>>(hH, rowp, ev, dinv, b1, bufB, sumsL1, NN);

    // ---- layer 2 (BN1+ReLU+residual fused into GEMM2 staging; h1 -> bufC) ----
    k_gemm<<<gemm_grid, 256, 0, stream>>>(bufB, x, sumsL1, g1, be1, bufC,
                                          dinv, W2, hH, NN);
    k_agg<<<agg_grid, 256, 0, stream>>>(hH, rowp, ev, dinv, b2, bufB, sumsL2, NN);
    k_bn<<<ew_grid, 256, 0, stream>>>(bufB, bufC, sumsL2, g2, be2, Wa, ba,
                                      bufC, evec, Zb, NN);   // in-place res ok

    // ---- output ----
    k_out<<<ew_grid, 256, 0, stream>>>(bufC, evec, Zb, out, NN);
}

// Round 11
// 259.230 us; speedup vs baseline: 1.5749x; 1.0357x over previous
//
#include <hip/hip_runtime.h>
#include <hip/hip_fp16.h>

#define NN 50000
#define DD 128
#define NE 800000
#define BN_EPS 1e-5f
#define NBUCK 196           // ceil(NN/256): bucket = dst>>8, 256 nodes per bucket
#define TILE_A 4096         // edges per k_binA block
#define BCAP 5120           // fixed staging capacity per bucket (mean 4096, 16 sigma)

typedef _Float16 f16x8 __attribute__((ext_vector_type(8)));
typedef float f32x4 __attribute__((ext_vector_type(4)));

// ---------------- phase A: bucket scatter into FIXED-CAPACITY staging ------------
__global__ __launch_bounds__(256) void k_binA(const int* __restrict__ src,
                                              const int* __restrict__ dst,
                                              int* __restrict__ bucketCur,
                                              unsigned* __restrict__ evS, int ne) {
    __shared__ int hcnt[NBUCK];
    __shared__ int hbase[NBUCK];
    int tid = threadIdx.x;
    for (int i = tid; i < NBUCK; i += 256) hcnt[i] = 0;
    __syncthreads();
    int base = blockIdx.x * TILE_A;
    int lim = ne - base;
    if (lim > TILE_A) lim = TILE_A;
    for (int i = tid; i < lim; i += 256) atomicAdd(&hcnt[dst[base + i] >> 8], 1);
    __syncthreads();
    for (int b = tid; b < NBUCK; b += 256) {
        hbase[b] = hcnt[b] ? (b * BCAP + atomicAdd(&bucketCur[b], hcnt[b])) : 0;
        hcnt[b] = 0;
    }
    __syncthreads();
    for (int i = tid; i < lim; i += 256) {
        int d = dst[base + i];
        int s = src[base + i];
        int bk = d >> 8;
        int rank = atomicAdd(&hcnt[bk], 1);
        evS[hbase[bk] + rank] = (unsigned)s | ((unsigned)(d & 255) << 16);
    }
}

// ---------------- phase B: per-bucket counting sort -> ev, rowp, dinv ------------
__global__ __launch_bounds__(256) void k_binB(const unsigned* __restrict__ evS,
                                              const int* __restrict__ bucketCur,
                                              unsigned* __restrict__ ev,
                                              int* __restrict__ rowp,
                                              float* __restrict__ dinv, int n) {
    __shared__ int sc[256];
    __shared__ int ncnt[256];
    __shared__ int ncur[256];
    int tid = threadIdx.x;
    int b = blockIdx.x;

    int v = (tid < NBUCK) ? bucketCur[tid] : 0;
    sc[tid] = v;
    __syncthreads();
    for (int off = 1; off < 256; off <<= 1) {
        int add = (tid >= off) ? sc[tid - off] : 0;
        __syncthreads();
        sc[tid] += add;
        __syncthreads();
    }
    int lo = sc[b] - ((b < NBUCK) ? bucketCur[b] : 0);   // exclusive base
    int cnt_b = bucketCur[b];
    int seg = b * BCAP;

    ncnt[tid] = 0;
    __syncthreads();
    for (int p = tid; p < cnt_b; p += 256)
        atomicAdd(&ncnt[evS[seg + p] >> 16], 1);
    __syncthreads();
    int nv = ncnt[tid];
    sc[tid] = nv;
    __syncthreads();
    for (int off = 1; off < 256; off <<= 1) {
        int add = (tid >= off) ? sc[tid - off] : 0;
        __syncthreads();
        sc[tid] += add;
        __syncthreads();
    }
    int nb = sc[tid] - nv;
    ncur[tid] = nb;
    int node = (b << 8) + tid;
    if (node < n) {
        rowp[node] = lo + nb;
        dinv[node] = 1.0f / sqrtf((float)(nv + 1));
    }
    if (b == NBUCK - 1 && tid == 0) rowp[n] = lo + cnt_b;
    __syncthreads();
    for (int p = tid; p < cnt_b; p += 256) {
        unsigned r = evS[seg + p];
        int ln = r >> 16;
        int rank = atomicAdd(&ncur[ln], 1);
        ev[lo + rank] = r & 0xFFFFu;
    }
}

// ---------------- GEMM: MFMA fp16, inline W conversion, fused BN prologue --------
// A input: fp32 (A) or fp16 (A16, layer 2 = agg1 output).  Hout (h1) written
// fp16 — identical to the MFMA A-input rounding, so the residual path is
// bit-consistent with the matmul path.
#define GTILE 64
__global__ __launch_bounds__(256) void k_gemm(const float* __restrict__ A,
                                              const __half* __restrict__ A16,
                                              const float* __restrict__ res,
                                              const float* __restrict__ sums,
                                              const float* __restrict__ gamma,
                                              const float* __restrict__ beta,
                                              __half* __restrict__ Hout,
                                              const float* __restrict__ dscale,
                                              const float* __restrict__ W,
                                              __half* __restrict__ C, int n) {
    __shared__ __half sW[DD * DD];       // 32 KB fragment-linear (no swizzle)
    __shared__ __half sA[GTILE * DD];    // 16 KB fragment-linear (swizzled)
    __shared__ float s_scale[DD], s_shift[DD];
    int tid = threadIdx.x;
    int wave = tid >> 6;
    int lane = tid & 63;
    bool fused = (res != nullptr);

    {   // stage W: fp32 -> fp16 B-fragment layout, in-kernel
        for (int s = tid; s < DD * DD / 8; s += 256) {
            int l = s & 63;
            int ks = (s >> 6) & 3;
            int cb = s >> 8;
            int col = cb * 16 + (l & 15);
            int kbase = ks * 32 + (l >> 4) * 8;
            __align__(16) __half tmp[8];
            #pragma unroll
            for (int j = 0; j < 8; j++)
                tmp[j] = __float2half_rn(W[(kbase + j) * DD + col]);
            *(uint4*)(sW + s * 8) = *(uint4*)tmp;
        }
    }
    if (fused && tid < DD) {
        float ssum = 0.f, qsum = 0.f;
        #pragma unroll
        for (int b = 0; b < 16; b++) {
            ssum += sums[b * 256 + tid];
            qsum += sums[b * 256 + 128 + tid];
        }
        float inv_n = 1.0f / (float)n;
        float mean = ssum * inv_n;
        float var = qsum * inv_n - mean * mean;
        float sc = gamma[tid] * (1.0f / sqrtf(var + BN_EPS));
        s_scale[tid] = sc;
        s_shift[tid] = beta[tid] - mean * sc;
    }

    int ntiles = (n + GTILE - 1) / GTILE;
    for (int t = blockIdx.x; t < ntiles; t += gridDim.x) {
        int row0 = t * GTILE;
        __syncthreads();   // covers W/stats stage (1st iter) + prev-tile reads
        {   // stage A tile: (optional BN+ReLU+res) -> fp16 fragments, swizzled
            for (int i = tid; i < GTILE * DD / 4; i += 256) {
                int r = i >> 5;         // row in tile
                int kq = i & 31;        // k = 4*kq
                bool rowok = (row0 + r < n);
                float4 v = make_float4(0.f, 0.f, 0.f, 0.f);
                if (rowok) {
                    if (A16 != nullptr) {
                        uint2 rawv = ((const uint2*)(A16 + (size_t)row0 * DD))[i];
                        const __half2* ap = (const __half2*)&rawv;
                        float2 a0 = __half22float2(ap[0]);
                        float2 a1 = __half22float2(ap[1]);
                        v = make_float4(a0.x, a0.y, a1.x, a1.y);
                    } else {
                        v = ((const float4*)(A + (size_t)row0 * DD))[i];
                    }
                }
                if (fused) {
                    float4 rv = make_float4(0.f, 0.f, 0.f, 0.f);
                    if (rowok) rv = ((const float4*)(res + (size_t)row0 * DD))[i];
                    int f4 = kq * 4;
                    v.x = fmaxf(v.x * s_scale[f4]     + s_shift[f4],     0.f) + rv.x;
                    v.y = fmaxf(v.y * s_scale[f4 + 1] + s_shift[f4 + 1], 0.f) + rv.y;
                    v.z = fmaxf(v.z * s_scale[f4 + 2] + s_shift[f4 + 2], 0.f) + rv.z;
                    v.w = fmaxf(v.w * s_scale[f4 + 3] + s_shift[f4 + 3], 0.f) + rv.w;
                }
                __half2 p0 = __floats2half2_rn(v.x, v.y);
                __half2 p1 = __floats2half2_rn(v.z, v.w);
                uint2 pk;
                pk.x = *(unsigned*)&p0;
                pk.y = *(unsigned*)&p1;
                if (fused && rowok)   // h1 residual table, fp16 (= MFMA rounding)
                    ((uint2*)(Hout + (size_t)row0 * DD))[i] = pk;
                int slot = ((r >> 4) * 4 + (kq >> 3)) * 64 +
                           (((kq >> 1) & 3) << 4) + (r & 15);
                int byte = slot * 16 + (kq & 1) * 8;
                byte ^= ((byte >> 9) & 7) << 4;
                *(uint2*)((char*)sA + byte) = pk;
            }
        }
        __syncthreads();

        f32x4 acc[8];
        #pragma unroll
        for (int cb = 0; cb < 8; cb++) acc[cb] = (f32x4)(0.0f);
        f16x8 af[4];
        #pragma unroll
        for (int ks = 0; ks < 4; ks++) {
            int rb = ((wave * 4 + ks) * 64 + lane) * 16;
            rb ^= ((rb >> 9) & 7) << 4;
            af[ks] = *(const f16x8*)((const char*)sA + rb);
        }
        #pragma unroll
        for (int cb = 0; cb < 8; cb++) {
            #pragma unroll
            for (int ks = 0; ks < 4; ks++) {
                f16x8 bf = *(const f16x8*)(sW + ((cb * 4 + ks) * 64 + lane) * 8);
                acc[cb] = __builtin_amdgcn_mfma_f32_16x16x32_f16(af[ks], bf,
                                                                 acc[cb], 0, 0, 0);
            }
        }

        // RACE FIX barrier: all waves' af ds_reads must retire before any wave
        // overwrites the staging buffer with its epilogue sC writes.
        __syncthreads();

        // per-row dinv scale for the fp16 gather table
        float dv[4];
        #pragma unroll
        for (int rr = 0; rr < 4; rr++) {
            int row = row0 + wave * 16 + (lane >> 4) * 4 + rr;
            dv[rr] = (row < n) ? dscale[row] : 1.f;
        }

        // epilogue: acc -> per-wave LDS region (col-xor spreads banks) -> coalesced
        __half* sC = sA + wave * (16 * DD);
        #pragma unroll
        for (int cb = 0; cb < 8; cb++) {
            int col = cb * 16 + (lane & 15);
            #pragma unroll
            for (int rr = 0; rr < 4; rr++) {
                int grow = (lane >> 4) * 4 + rr;
                sC[grow * DD + (col ^ ((grow & 3) << 4))] =
                    __float2half(acc[cb][rr] * dv[rr]);
            }
        }
        __syncthreads();
        #pragma unroll
        for (int i2 = 0; i2 < 4; i2++) {
            int o = (i2 * 64 + lane) * 8;   // half index in wave's 16x128 region
            int grow = o >> 7;
            int col0 = o & 127;
            int row = row0 + wave * 16 + grow;
            if (row < n) {
                uint4 val = *(uint4*)(sC + grow * DD + (col0 ^ ((grow & 3) << 4)));
                *(uint4*)(C + (size_t)row * DD + col0) = val;
            }
        }
    }
}

// ---------------- aggregation: 16 lanes/node, 4-deep pipelined gather ------------
// Output now fp16 (halves the write + downstream read traffic).
#define ACC8(raw) { const __half2* hp_ = (const __half2*)&(raw);               \
    float2 c0_ = __half22float2(hp_[0]); float2 c1_ = __half22float2(hp_[1]);  \
    float2 c2_ = __half22float2(hp_[2]); float2 c3_ = __half22float2(hp_[3]);  \
    a[0] += c0_.x; a[1] += c0_.y; a[2] += c1_.x; a[3] += c1_.y;                \
    a[4] += c2_.x; a[5] += c2_.y; a[6] += c3_.x; a[7] += c3_.y; }

__global__ __launch_bounds__(256) void k_agg(const __half* __restrict__ h,
                                             const int* __restrict__ rowp,
                                             const unsigned* __restrict__ ev,
                                             const float* __restrict__ dinv,
                                             const float* __restrict__ bias,
                                             __half* __restrict__ out,
                                             float* __restrict__ sums, int n) {
    int tid = threadIdx.x;
    int grp = tid >> 4;            // node within block 0..15
    int m = tid & 15;              // 16 B chunk within row
    int node = blockIdx.x * 16 + grp;
    bool activ = node < n;

    int beg = 0, end = 0;
    float di = 0.f;
    if (activ) { beg = rowp[node]; end = rowp[node + 1]; di = dinv[node]; }

    float sf[8] = {0.f, 0.f, 0.f, 0.f, 0.f, 0.f, 0.f, 0.f};
    float bf[8];
    {
        float4 b0 = *(const float4*)(bias + m * 8);
        float4 b1 = *(const float4*)(bias + m * 8 + 4);
        bf[0] = b0.x; bf[1] = b0.y; bf[2] = b0.z; bf[3] = b0.w;
        bf[4] = b1.x; bf[5] = b1.y; bf[6] = b1.z; bf[7] = b1.w;
        if (activ) {
            float4 raw = *(const float4*)(h + (size_t)node * DD + m * 8);
            const __half2* hp = (const __half2*)&raw;
            float2 s0 = __half22float2(hp[0]);
            float2 s1 = __half22float2(hp[1]);
            float2 s2 = __half22float2(hp[2]);
            float2 s3 = __half22float2(hp[3]);
            sf[0] = s0.x; sf[1] = s0.y; sf[2] = s1.x; sf[3] = s1.y;
            sf[4] = s2.x; sf[5] = s2.y; sf[6] = s3.x; sf[7] = s3.y;
        }
    }

    float a[8] = {0.f, 0.f, 0.f, 0.f, 0.f, 0.f, 0.f, 0.f};
    int e = beg;
    int cnt4 = (end - beg) >> 2;
    if (cnt4 > 0) {
        unsigned s0 = ev[e], s1 = ev[e + 1], s2 = ev[e + 2], s3 = ev[e + 3];
        float4 r0 = *(const float4*)(h + (size_t)s0 * DD + m * 8);
        float4 r1 = *(const float4*)(h + (size_t)s1 * DD + m * 8);
        float4 r2 = *(const float4*)(h + (size_t)s2 * DD + m * 8);
        float4 r3 = *(const float4*)(h + (size_t)s3 * DD + m * 8);
        for (int g = 1; g < cnt4; g++) {
            e += 4;
            unsigned t0 = ev[e], t1 = ev[e + 1], t2 = ev[e + 2], t3 = ev[e + 3];
            float4 q0 = *(const float4*)(h + (size_t)t0 * DD + m * 8);
            float4 q1 = *(const float4*)(h + (size_t)t1 * DD + m * 8);
            float4 q2 = *(const float4*)(h + (size_t)t2 * DD + m * 8);
            float4 q3 = *(const float4*)(h + (size_t)t3 * DD + m * 8);
            ACC8(r0); ACC8(r1); ACC8(r2); ACC8(r3);
            r0 = q0; r1 = q1; r2 = q2; r3 = q3;
        }
        ACC8(r0); ACC8(r1); ACC8(r2); ACC8(r3);
        e += 4;
    }
    for (; e < end; e++) {
        unsigned s = ev[e];
        float4 raw = *(const float4*)(h + (size_t)s * DD + m * 8);
        ACC8(raw);
    }

    float o[8];
    #pragma unroll
    for (int j = 0; j < 8; j++) o[j] = di * (a[j] + sf[j]) + bf[j];
    if (activ) {
        __half2 p0 = __floats2half2_rn(o[0], o[1]);
        __half2 p1 = __floats2half2_rn(o[2], o[3]);
        __half2 p2 = __floats2half2_rn(o[4], o[5]);
        __half2 p3 = __floats2half2_rn(o[6], o[7]);
        uint4 pk;
        pk.x = *(unsigned*)&p0; pk.y = *(unsigned*)&p1;
        pk.z = *(unsigned*)&p2; pk.w = *(unsigned*)&p3;
        *(uint4*)(out + (size_t)node * DD + m * 8) = pk;
    }

    __shared__ float rs[16][132];            // +4 pad breaks 128-stride conflicts
    #pragma unroll
    for (int j = 0; j < 8; j++) rs[grp][m * 8 + j] = activ ? o[j] : 0.f;
    __syncthreads();

    int bank = blockIdx.x & 15;
    if (tid < 128) {
        float s = 0.f;
        #pragma unroll
        for (int r2 = 0; r2 < 16; r2++) s += rs[r2][tid];
        atomicAdd(&sums[bank * 256 + tid], s);
    } else {
        int f = tid - 128;
        float q = 0.f;
        #pragma unroll
        for (int r2 = 0; r2 < 16; r2++) { float v = rs[r2][f]; q += v * v; }
        atomicAdd(&sums[bank * 256 + 128 + f], q);
    }
}

// ---------------- BN apply + ReLU + residual + fused attention score (layer 2) ----
// X (agg2 out) and res (h1) now fp16 inputs; h2 written fp16.
__global__ __launch_bounds__(256) void k_bn(const __half* __restrict__ X,
                                            const __half* __restrict__ res,
                                            const float* __restrict__ sums,
                                            const float* __restrict__ gamma,
                                            const float* __restrict__ beta,
                                            const float* __restrict__ Wa,
                                            const float* __restrict__ ba,
                                            __half* __restrict__ out,
                                            float* __restrict__ evec,
                                            float* __restrict__ Zb, int n) {
    __shared__ float s_scale[128], s_shift[128];
    if (threadIdx.x < 128) {
        int ff = threadIdx.x;
        float ssum = 0.f, qsum = 0.f;
        #pragma unroll
        for (int b = 0; b < 16; b++) {
            ssum += sums[b * 256 + ff];
            qsum += sums[b * 256 + 128 + ff];
        }
        float inv_n = 1.0f / (float)n;
        float mean = ssum * inv_n;
        float var = qsum * inv_n - mean * mean;
        float sc = gamma[ff] * (1.0f / sqrtf(var + BN_EPS));
        s_scale[ff] = sc;
        s_shift[ff] = beta[ff] - mean * sc;
    }
    __syncthreads();
    int idx = blockIdx.x * 256 + threadIdx.x;
    int total = n * (DD / 4);
    int f = (threadIdx.x & 31) * 4;
    float o[4] = {0.f, 0.f, 0.f, 0.f};
    if (idx < total) {
        uint2 xv = ((const uint2*)X)[idx];
        uint2 rw = ((const uint2*)res)[idx];
        const __half2* xp = (const __half2*)&xv;
        const __half2* rp = (const __half2*)&rw;
        float2 x0 = __half22float2(xp[0]), x1 = __half22float2(xp[1]);
        float2 r0 = __half22float2(rp[0]), r1 = __half22float2(rp[1]);
        float vi[4] = {x0.x, x0.y, x1.x, x1.y};
        float ri[4] = {r0.x, r0.y, r1.x, r1.y};
        #pragma unroll
        for (int j = 0; j < 4; j++) {
            float x = vi[j] * s_scale[f + j] + s_shift[f + j];
            x = fmaxf(x, 0.f);
            o[j] = x + ri[j];
        }
        __half2 o0 = __floats2half2_rn(o[0], o[1]);
        __half2 o1 = __floats2half2_rn(o[2], o[3]);
        uint2 ov;
        ov.x = *(unsigned*)&o0;
        ov.y = *(unsigned*)&o1;
        ((uint2*)out)[idx] = ov;
    }
    if (Wa != nullptr) {
        float t = 0.f;
        if (idx < total) {
            float4 wv = *(const float4*)(Wa + f);
            t = o[0] * wv.x + o[1] * wv.y + o[2] * wv.z + o[3] * wv.w;
        }
        #pragma unroll
        for (int m = 16; m >= 1; m >>= 1) t += __shfl_xor(t, m);
        __shared__ float part[8];
        if ((threadIdx.x & 31) == 0) {
            float ev = 0.f;
            if (idx < total) {
                ev = expf(tanhf(t + ba[0]));
                evec[idx >> 5] = ev;
            }
            part[threadIdx.x >> 5] = ev;
        }
        __syncthreads();
        if (threadIdx.x == 0) {
            float z = part[0] + part[1] + part[2] + part[3] +
                      part[4] + part[5] + part[6] + part[7];
            atomicAdd(&Zb[blockIdx.x & 63], z);
        }
    }
}

// ---------------- final: out = h2(fp16) * e / Z (Z from 64 banks) ----------------
__global__ __launch_bounds__(256) void k_out(const __half* __restrict__ H,
                                             const float* __restrict__ evec,
                                             const float* __restrict__ Zb,
                                             float* __restrict__ out, int n) {
    __shared__ float sZ;
    if (threadIdx.x == 0) {
        float z = 0.f;
        #pragma unroll
        for (int i = 0; i < 64; i++) z += Zb[i];
        sZ = z;
    }
    __syncthreads();
    int idx = blockIdx.x * blockDim.x + threadIdx.x;
    int total = n * (DD / 4);
    if (idx >= total) return;
    int node = idx >> 5;
    float s = evec[node] / sZ;
    uint2 hv = ((const uint2*)H)[idx];
    const __half2* hp = (const __half2*)&hv;
    float2 h0 = __half22float2(hp[0]), h1 = __half22float2(hp[1]);
    ((float4*)out)[idx] = make_float4(h0.x * s, h0.y * s, h1.x * s, h1.y * s);
}

extern "C" void kernel_launch(void* const* d_in, const int* in_sizes, int n_in,
                              void* d_out, int out_size, void* d_ws, size_t ws_size,
                              hipStream_t stream) {
    const float* x   = (const float*)d_in[0];
    const int* eidx  = (const int*)d_in[1];
    const float* W1  = (const float*)d_in[2];
    const float* b1  = (const float*)d_in[3];
    const float* g1  = (const float*)d_in[4];
    const float* be1 = (const float*)d_in[5];
    const float* W2  = (const float*)d_in[6];
    const float* b2  = (const float*)d_in[7];
    const float* g2  = (const float*)d_in[8];
    const float* be2 = (const float*)d_in[9];
    const float* Wa  = (const float*)d_in[10];
    const float* ba  = (const float*)d_in[11];
    float* out = (float*)d_out;

    const int* srcp = eidx;
    const int* dstp = eidx + NE;

    float* bufA = (float*)d_ws;              // N*D f32 region; fp16 gather table
    float* bufB = bufA + (size_t)NN * DD;    // N*D region (evS staging / agg out fp16)
    float* bufC = bufB + (size_t)NN * DD;    // N*D region (h1 / h2 fp16)
    unsigned* ev = (unsigned*)(bufC + (size_t)NN * DD);   // NE 4B records (src)
    float* dinv = (float*)(ev + NE);         // NN
    float* evec = dinv + NN;                 // NN
    // zeroed region (one memset): bucketCur(256) | sums(8192) | Zb(64)
    int* bucketCur = (int*)(evec + NN);      // 256 (NBUCK used)
    float* sums = (float*)(bucketCur + 256); // 2 layers x 16 banks x 256 = 8192
    float* Zb   = sums + 8192;               // 64 banks
    int* rowp   = (int*)(Zb + 64);           // NN+1 (pad 64)

    __half* hH  = (__half*)bufA;             // fp16 gather table, 12.8 MB
    unsigned* evS = (unsigned*)bufB;         // staged: NBUCK*BCAP*4B = 4.0 MB
    __half* hAgg = (__half*)bufB;            // fp16 agg output (evS consumed before)
    __half* hRes = (__half*)bufC;            // fp16 h1, then h2 in-place

    float* sumsL1 = sums;
    float* sumsL2 = sums + 4096;

    // ---- CSR build: 1 memset + 2 kernels ----
    hipMemsetAsync(bucketCur, 0, (size_t)(256 + 8192 + 64) * sizeof(int), stream);
    const int nA = (NE + TILE_A - 1) / TILE_A;       // 196
    k_binA<<<nA, 256, 0, stream>>>(srcp, dstp, bucketCur, evS, NE);
    k_binB<<<NBUCK, 256, 0, stream>>>(evS, bucketCur, ev, rowp, dinv, NN);

    int gemm_grid = (NN + GTILE - 1) / GTILE;        // 782
    int agg_grid  = (NN + 15) / 16;                  // 3125
    int ew_grid   = (NN * (DD / 4) + 255) / 256;     // 6250

    // ---- layer 1 (GEMM from x fp32; table scaled by dinv) ----
    k_gemm<<<gemm_grid, 256, 0, stream>>>(x, nullptr, nullptr, nullptr, nullptr,
                                          nullptr, nullptr, dinv, W1, hH, NN);
    k_agg<<<agg_grid, 256, 0, stream>>>(hH, rowp, ev, dinv, b1, hAgg, sumsL1, NN);

    // ---- layer 2 (BN1+ReLU+residual fused into GEMM2 staging; h1 fp16 -> bufC) --
    k_gemm<<<gemm_grid, 256, 0, stream>>>(nullptr, hAgg, x, sumsL1, g1, be1,
                                          hRes, dinv, W2, hH, NN);
    k_agg<<<agg_grid, 256, 0, stream>>>(hH, rowp, ev, dinv, b2, hAgg, sumsL2, NN);
    k_bn<<<ew_grid, 256, 0, stream>>>(hAgg, hRes, sumsL2, g2, be2, Wa, ba,
                                      hRes, evec, Zb, NN);   // in-place res ok

    // ---- output ----
    k_out<<<ew_grid, 256, 0, stream>>>(hRes, evec, Zb, out, NN);
}

// Round 12
// 256.007 us; speedup vs baseline: 1.5947x; 1.0126x over previous
//
#include <hip/hip_runtime.h>
#include <hip/hip_fp16.h>

#define NN 50000
#define DD 128
#define NE 800000
#define BN_EPS 1e-5f
#define NBUCK 196           // ceil(NN/256): bucket = dst>>8, 256 nodes per bucket
#define TILE_A 4096         // edges per k_binA block (196*4096 >= 800000)
#define SUBCAP 64           // records per (block,bucket) sub-segment; P(overflow)~1e-9

typedef _Float16 f16x8 __attribute__((ext_vector_type(8)));
typedef float f32x4 __attribute__((ext_vector_type(4)));

// ---------------- phase A: sub-segmented bucket scatter (no global cursor) -------
// Each (block,bucket) owns a private SUBCAP-record slot in evS, so no global
// atomics and no pre-zeroed cursor -> the memset dispatch is gone.  Per-pair
// counts go to bcnt[bucket*NBUCK+blk] (written unconditionally, needs no init).
// Block 0 also zeroes the sums/Zb stat region (consumed >=2 dispatches later).
__global__ __launch_bounds__(256) void k_binA(const int* __restrict__ src,
                                              const int* __restrict__ dst,
                                              int* __restrict__ bcnt,
                                              unsigned* __restrict__ evS,
                                              float* __restrict__ sumsZ, int ne) {
    __shared__ int hcnt[NBUCK];
    int tid = threadIdx.x;
    int blk = blockIdx.x;
    if (blk == 0) {
        for (int i = tid; i < 8256; i += 256) sumsZ[i] = 0.f;   // sums(8192)+Zb(64)
    }
    for (int i = tid; i < NBUCK; i += 256) hcnt[i] = 0;
    __syncthreads();
    int base = blk * TILE_A;
    int lim = ne - base;
    if (lim > TILE_A) lim = TILE_A;
    for (int i = tid; i < lim; i += 256) atomicAdd(&hcnt[dst[base + i] >> 8], 1);
    __syncthreads();
    for (int b = tid; b < NBUCK; b += 256) {
        bcnt[b * NBUCK + blk] = hcnt[b];
        hcnt[b] = 0;
    }
    __syncthreads();
    for (int i = tid; i < lim; i += 256) {
        int d = dst[base + i];
        int s = src[base + i];
        int bk = d >> 8;
        int rank = atomicAdd(&hcnt[bk], 1);
        if (rank < SUBCAP)   // clamp guard (statistically unreachable)
            evS[(size_t)(bk * NBUCK + blk) * SUBCAP + rank] =
                (unsigned)s | ((unsigned)(d & 255) << 16);
    }
}

// ---------------- phase B: per-bucket counting sort -> ev, rowp, dinv ------------
// One block per bucket.  Thread j sums bucket j's sub-counts (contiguous row of
// bcnt) for the global scan; then gathers its bucket's 196 sub-runs.
__global__ __launch_bounds__(256) void k_binB(const unsigned* __restrict__ evS,
                                              const int* __restrict__ bcnt,
                                              unsigned* __restrict__ ev,
                                              int* __restrict__ rowp,
                                              float* __restrict__ dinv, int n) {
    __shared__ int sc[256];
    __shared__ int ncnt[256];
    __shared__ int ncur[256];
    __shared__ int s_lo, s_cnt;
    int tid = threadIdx.x;
    int b = blockIdx.x;

    // bucket totals (thread j = bucket j) + global exclusive scan
    int tot = 0;
    if (tid < NBUCK) {
        const int* row = bcnt + tid * NBUCK;
        for (int j = 0; j < NBUCK; j++) {
            int c = row[j];
            tot += (c > SUBCAP) ? SUBCAP : c;
        }
    }
    sc[tid] = tot;
    __syncthreads();
    for (int off = 1; off < 256; off <<= 1) {
        int add = (tid >= off) ? sc[tid - off] : 0;
        __syncthreads();
        sc[tid] += add;
        __syncthreads();
    }
    if (tid == b) { s_lo = sc[tid] - tot; s_cnt = tot; }
    __syncthreads();
    int lo = s_lo;
    int cnt_b = s_cnt;

    // this bucket's sub-run count for thread j
    int c = 0;
    if (tid < NBUCK) {
        c = bcnt[b * NBUCK + tid];
        if (c > SUBCAP) c = SUBCAP;
    }
    size_t sbase = (size_t)(b * NBUCK + tid) * SUBCAP;

    // node histogram over the bucket's records
    ncnt[tid] = 0;
    __syncthreads();
    for (int r = 0; r < c; r++)
        atomicAdd(&ncnt[evS[sbase + r] >> 16], 1);
    __syncthreads();
    int nv = ncnt[tid];
    sc[tid] = nv;
    __syncthreads();
    for (int off = 1; off < 256; off <<= 1) {
        int add = (tid >= off) ? sc[tid - off] : 0;
        __syncthreads();
        sc[tid] += add;
        __syncthreads();
    }
    int nb = sc[tid] - nv;
    ncur[tid] = nb;
    int node = (b << 8) + tid;
    if (node < n) {
        rowp[node] = lo + nb;
        dinv[node] = 1.0f / sqrtf((float)(nv + 1));
    }
    if (b == NBUCK - 1 && tid == 0) rowp[n] = lo + cnt_b;
    __syncthreads();
    // scatter sub-runs into node-sorted ev
    for (int r = 0; r < c; r++) {
        unsigned rec = evS[sbase + r];
        int ln = rec >> 16;
        int pos = atomicAdd(&ncur[ln], 1);
        ev[lo + pos] = rec & 0xFFFFu;
    }
}

// ---------------- GEMM: MFMA fp16, inline W conversion, fused BN prologue --------
// Grid 512 persistent (2 blocks/CU): W fragment conversion amortized over ~1.5
// tiles/block instead of paid 782x.
#define GTILE 64
#define GEMM_GRID 512
__global__ __launch_bounds__(256) void k_gemm(const float* __restrict__ A,
                                              const __half* __restrict__ A16,
                                              const float* __restrict__ res,
                                              const float* __restrict__ sums,
                                              const float* __restrict__ gamma,
                                              const float* __restrict__ beta,
                                              __half* __restrict__ Hout,
                                              const float* __restrict__ dscale,
                                              const float* __restrict__ W,
                                              __half* __restrict__ C, int n) {
    __shared__ __half sW[DD * DD];       // 32 KB fragment-linear (no swizzle)
    __shared__ __half sA[GTILE * DD];    // 16 KB fragment-linear (swizzled)
    __shared__ float s_scale[DD], s_shift[DD];
    int tid = threadIdx.x;
    int wave = tid >> 6;
    int lane = tid & 63;
    bool fused = (res != nullptr);

    {   // stage W: fp32 -> fp16 B-fragment layout, in-kernel (once per block)
        for (int s = tid; s < DD * DD / 8; s += 256) {
            int l = s & 63;
            int ks = (s >> 6) & 3;
            int cb = s >> 8;
            int col = cb * 16 + (l & 15);
            int kbase = ks * 32 + (l >> 4) * 8;
            __align__(16) __half tmp[8];
            #pragma unroll
            for (int j = 0; j < 8; j++)
                tmp[j] = __float2half_rn(W[(kbase + j) * DD + col]);
            *(uint4*)(sW + s * 8) = *(uint4*)tmp;
        }
    }
    if (fused && tid < DD) {
        float ssum = 0.f, qsum = 0.f;
        #pragma unroll
        for (int b = 0; b < 16; b++) {
            ssum += sums[b * 256 + tid];
            qsum += sums[b * 256 + 128 + tid];
        }
        float inv_n = 1.0f / (float)n;
        float mean = ssum * inv_n;
        float var = qsum * inv_n - mean * mean;
        float sc = gamma[tid] * (1.0f / sqrtf(var + BN_EPS));
        s_scale[tid] = sc;
        s_shift[tid] = beta[tid] - mean * sc;
    }

    int ntiles = (n + GTILE - 1) / GTILE;
    for (int t = blockIdx.x; t < ntiles; t += gridDim.x) {
        int row0 = t * GTILE;
        __syncthreads();   // covers W/stats stage (1st iter) + prev-tile reads
        {   // stage A tile: (optional BN+ReLU+res) -> fp16 fragments, swizzled
            for (int i = tid; i < GTILE * DD / 4; i += 256) {
                int r = i >> 5;         // row in tile
                int kq = i & 31;        // k = 4*kq
                bool rowok = (row0 + r < n);
                float4 v = make_float4(0.f, 0.f, 0.f, 0.f);
                if (rowok) {
                    if (A16 != nullptr) {
                        uint2 rawv = ((const uint2*)(A16 + (size_t)row0 * DD))[i];
                        const __half2* ap = (const __half2*)&rawv;
                        float2 a0 = __half22float2(ap[0]);
                        float2 a1 = __half22float2(ap[1]);
                        v = make_float4(a0.x, a0.y, a1.x, a1.y);
                    } else {
                        v = ((const float4*)(A + (size_t)row0 * DD))[i];
                    }
                }
                if (fused) {
                    float4 rv = make_float4(0.f, 0.f, 0.f, 0.f);
                    if (rowok) rv = ((const float4*)(res + (size_t)row0 * DD))[i];
                    int f4 = kq * 4;
                    v.x = fmaxf(v.x * s_scale[f4]     + s_shift[f4],     0.f) + rv.x;
                    v.y = fmaxf(v.y * s_scale[f4 + 1] + s_shift[f4 + 1], 0.f) + rv.y;
                    v.z = fmaxf(v.z * s_scale[f4 + 2] + s_shift[f4 + 2], 0.f) + rv.z;
                    v.w = fmaxf(v.w * s_scale[f4 + 3] + s_shift[f4 + 3], 0.f) + rv.w;
                }
                __half2 p0 = __floats2half2_rn(v.x, v.y);
                __half2 p1 = __floats2half2_rn(v.z, v.w);
                uint2 pk;
                pk.x = *(unsigned*)&p0;
                pk.y = *(unsigned*)&p1;
                if (fused && rowok)   // h1 residual table, fp16 (= MFMA rounding)
                    ((uint2*)(Hout + (size_t)row0 * DD))[i] = pk;
                int slot = ((r >> 4) * 4 + (kq >> 3)) * 64 +
                           (((kq >> 1) & 3) << 4) + (r & 15);
                int byte = slot * 16 + (kq & 1) * 8;
                byte ^= ((byte >> 9) & 7) << 4;
                *(uint2*)((char*)sA + byte) = pk;
            }
        }
        __syncthreads();

        f32x4 acc[8];
        #pragma unroll
        for (int cb = 0; cb < 8; cb++) acc[cb] = (f32x4)(0.0f);
        f16x8 af[4];
        #pragma unroll
        for (int ks = 0; ks < 4; ks++) {
            int rb = ((wave * 4 + ks) * 64 + lane) * 16;
            rb ^= ((rb >> 9) & 7) << 4;
            af[ks] = *(const f16x8*)((const char*)sA + rb);
        }
        #pragma unroll
        for (int cb = 0; cb < 8; cb++) {
            #pragma unroll
            for (int ks = 0; ks < 4; ks++) {
                f16x8 bf = *(const f16x8*)(sW + ((cb * 4 + ks) * 64 + lane) * 8);
                acc[cb] = __builtin_amdgcn_mfma_f32_16x16x32_f16(af[ks], bf,
                                                                 acc[cb], 0, 0, 0);
            }
        }

        // RACE FIX barrier: all waves' af ds_reads must retire before any wave
        // overwrites the staging buffer with its epilogue sC writes.
        __syncthreads();

        // per-row dinv scale for the fp16 gather table
        float dv[4];
        #pragma unroll
        for (int rr = 0; rr < 4; rr++) {
            int row = row0 + wave * 16 + (lane >> 4) * 4 + rr;
            dv[rr] = (row < n) ? dscale[row] : 1.f;
        }

        // epilogue: acc -> per-wave LDS region (col-xor spreads banks) -> coalesced
        __half* sC = sA + wave * (16 * DD);
        #pragma unroll
        for (int cb = 0; cb < 8; cb++) {
            int col = cb * 16 + (lane & 15);
            #pragma unroll
            for (int rr = 0; rr < 4; rr++) {
                int grow = (lane >> 4) * 4 + rr;
                sC[grow * DD + (col ^ ((grow & 3) << 4))] =
                    __float2half(acc[cb][rr] * dv[rr]);
            }
        }
        __syncthreads();
        #pragma unroll
        for (int i2 = 0; i2 < 4; i2++) {
            int o = (i2 * 64 + lane) * 8;   // half index in wave's 16x128 region
            int grow = o >> 7;
            int col0 = o & 127;
            int row = row0 + wave * 16 + grow;
            if (row < n) {
                uint4 val = *(uint4*)(sC + grow * DD + (col0 ^ ((grow & 3) << 4)));
                *(uint4*)(C + (size_t)row * DD + col0) = val;
            }
        }
    }
}

// ---------------- aggregation: 16 lanes/node, dual-bank pipelined gather ---------
// Two accumulator banks (a/b) break the per-channel dependent fp32-add chain
// across the 4 unrolled edges; merged at the end.
#define ACC8T(acc, raw) { const __half2* hp_ = (const __half2*)&(raw);         \
    float2 c0_ = __half22float2(hp_[0]); float2 c1_ = __half22float2(hp_[1]);  \
    float2 c2_ = __half22float2(hp_[2]); float2 c3_ = __half22float2(hp_[3]);  \
    acc[0] += c0_.x; acc[1] += c0_.y; acc[2] += c1_.x; acc[3] += c1_.y;        \
    acc[4] += c2_.x; acc[5] += c2_.y; acc[6] += c3_.x; acc[7] += c3_.y; }

__global__ __launch_bounds__(256) void k_agg(const __half* __restrict__ h,
                                             const int* __restrict__ rowp,
                                             const unsigned* __restrict__ ev,
                                             const float* __restrict__ dinv,
                                             const float* __restrict__ bias,
                                             __half* __restrict__ out,
                                             float* __restrict__ sums, int n) {
    int tid = threadIdx.x;
    int grp = tid >> 4;            // node within block 0..15
    int m = tid & 15;              // 16 B chunk within row
    int node = blockIdx.x * 16 + grp;
    bool activ = node < n;

    int beg = 0, end = 0;
    float di = 0.f;
    if (activ) { beg = rowp[node]; end = rowp[node + 1]; di = dinv[node]; }

    float sf[8] = {0.f, 0.f, 0.f, 0.f, 0.f, 0.f, 0.f, 0.f};
    float bf[8];
    {
        float4 b0 = *(const float4*)(bias + m * 8);
        float4 b1 = *(const float4*)(bias + m * 8 + 4);
        bf[0] = b0.x; bf[1] = b0.y; bf[2] = b0.z; bf[3] = b0.w;
        bf[4] = b1.x; bf[5] = b1.y; bf[6] = b1.z; bf[7] = b1.w;
        if (activ) {
            float4 raw = *(const float4*)(h + (size_t)node * DD + m * 8);
            const __half2* hp = (const __half2*)&raw;
            float2 s0 = __half22float2(hp[0]);
            float2 s1 = __half22float2(hp[1]);
            float2 s2 = __half22float2(hp[2]);
            float2 s3 = __half22float2(hp[3]);
            sf[0] = s0.x; sf[1] = s0.y; sf[2] = s1.x; sf[3] = s1.y;
            sf[4] = s2.x; sf[5] = s2.y; sf[6] = s3.x; sf[7] = s3.y;
        }
    }

    float a[8] = {0.f, 0.f, 0.f, 0.f, 0.f, 0.f, 0.f, 0.f};
    float a2[8] = {0.f, 0.f, 0.f, 0.f, 0.f, 0.f, 0.f, 0.f};
    int e = beg;
    int cnt4 = (end - beg) >> 2;
    if (cnt4 > 0) {
        unsigned s0 = ev[e], s1 = ev[e + 1], s2 = ev[e + 2], s3 = ev[e + 3];
        float4 r0 = *(const float4*)(h + (size_t)s0 * DD + m * 8);
        float4 r1 = *(const float4*)(h + (size_t)s1 * DD + m * 8);
        float4 r2 = *(const float4*)(h + (size_t)s2 * DD + m * 8);
        float4 r3 = *(const float4*)(h + (size_t)s3 * DD + m * 8);
        for (int g = 1; g < cnt4; g++) {
            e += 4;
            unsigned t0 = ev[e], t1 = ev[e + 1], t2 = ev[e + 2], t3 = ev[e + 3];
            float4 q0 = *(const float4*)(h + (size_t)t0 * DD + m * 8);
            float4 q1 = *(const float4*)(h + (size_t)t1 * DD + m * 8);
            float4 q2 = *(const float4*)(h + (size_t)t2 * DD + m * 8);
            float4 q3 = *(const float4*)(h + (size_t)t3 * DD + m * 8);
            ACC8T(a, r0); ACC8T(a2, r1); ACC8T(a, r2); ACC8T(a2, r3);
            r0 = q0; r1 = q1; r2 = q2; r3 = q3;
        }
        ACC8T(a, r0); ACC8T(a2, r1); ACC8T(a, r2); ACC8T(a2, r3);
        e += 4;
    }
    for (; e < end; e++) {
        unsigned s = ev[e];
        float4 raw = *(const float4*)(h + (size_t)s * DD + m * 8);
        ACC8T(a, raw);
    }
    #pragma unroll
    for (int j = 0; j < 8; j++) a[j] += a2[j];

    float o[8];
    #pragma unroll
    for (int j = 0; j < 8; j++) o[j] = di * (a[j] + sf[j]) + bf[j];
    if (activ) {
        __half2 p0 = __floats2half2_rn(o[0], o[1]);
        __half2 p1 = __floats2half2_rn(o[2], o[3]);
        __half2 p2 = __floats2half2_rn(o[4], o[5]);
        __half2 p3 = __floats2half2_rn(o[6], o[7]);
        uint4 pk;
        pk.x = *(unsigned*)&p0; pk.y = *(unsigned*)&p1;
        pk.z = *(unsigned*)&p2; pk.w = *(unsigned*)&p3;
        *(uint4*)(out + (size_t)node * DD + m * 8) = pk;
    }

    __shared__ float rs[16][132];            // +4 pad breaks 128-stride conflicts
    #pragma unroll
    for (int j = 0; j < 8; j++) rs[grp][m * 8 + j] = activ ? o[j] : 0.f;
    __syncthreads();

    int bank = blockIdx.x & 15;
    if (tid < 128) {
        float s = 0.f;
        #pragma unroll
        for (int r2 = 0; r2 < 16; r2++) s += rs[r2][tid];
        atomicAdd(&sums[bank * 256 + tid], s);
    } else {
        int f = tid - 128;
        float q = 0.f;
        #pragma unroll
        for (int r2 = 0; r2 < 16; r2++) { float v = rs[r2][f]; q += v * v; }
        atomicAdd(&sums[bank * 256 + 128 + f], q);
    }
}

// ---------------- BN apply + ReLU + residual + fused attention score (layer 2) ----
__global__ __launch_bounds__(256) void k_bn(const __half* __restrict__ X,
                                            const __half* __restrict__ res,
                                            const float* __restrict__ sums,
                                            const float* __restrict__ gamma,
                                            const float* __restrict__ beta,
                                            const float* __restrict__ Wa,
                                            const float* __restrict__ ba,
                                            __half* __restrict__ out,
                                            float* __restrict__ evec,
                                            float* __restrict__ Zb, int n) {
    __shared__ float s_scale[128], s_shift[128];
    if (threadIdx.x < 128) {
        int ff = threadIdx.x;
        float ssum = 0.f, qsum = 0.f;
        #pragma unroll
        for (int b = 0; b < 16; b++) {
            ssum += sums[b * 256 + ff];
            qsum += sums[b * 256 + 128 + ff];
        }
        float inv_n = 1.0f / (float)n;
        float mean = ssum * inv_n;
        float var = qsum * inv_n - mean * mean;
        float sc = gamma[ff] * (1.0f / sqrtf(var + BN_EPS));
        s_scale[ff] = sc;
        s_shift[ff] = beta[ff] - mean * sc;
    }
    __syncthreads();
    int idx = blockIdx.x * 256 + threadIdx.x;
    int total = n * (DD / 4);
    int f = (threadIdx.x & 31) * 4;
    float o[4] = {0.f, 0.f, 0.f, 0.f};
    if (idx < total) {
        uint2 xv = ((const uint2*)X)[idx];
        uint2 rw = ((const uint2*)res)[idx];
        const __half2* xp = (const __half2*)&xv;
        const __half2* rp = (const __half2*)&rw;
        float2 x0 = __half22float2(xp[0]), x1 = __half22float2(xp[1]);
        float2 r0 = __half22float2(rp[0]), r1 = __half22float2(rp[1]);
        float vi[4] = {x0.x, x0.y, x1.x, x1.y};
        float ri[4] = {r0.x, r0.y, r1.x, r1.y};
        #pragma unroll
        for (int j = 0; j < 4; j++) {
            float x = vi[j] * s_scale[f + j] + s_shift[f + j];
            x = fmaxf(x, 0.f);
            o[j] = x + ri[j];
        }
        __half2 o0 = __floats2half2_rn(o[0], o[1]);
        __half2 o1 = __floats2half2_rn(o[2], o[3]);
        uint2 ov;
        ov.x = *(unsigned*)&o0;
        ov.y = *(unsigned*)&o1;
        ((uint2*)out)[idx] = ov;
    }
    if (Wa != nullptr) {
        float t = 0.f;
        if (idx < total) {
            float4 wv = *(const float4*)(Wa + f);
            t = o[0] * wv.x + o[1] * wv.y + o[2] * wv.z + o[3] * wv.w;
        }
        #pragma unroll
        for (int m = 16; m >= 1; m >>= 1) t += __shfl_xor(t, m);
        __shared__ float part[8];
        if ((threadIdx.x & 31) == 0) {
            float ev = 0.f;
            if (idx < total) {
                ev = expf(tanhf(t + ba[0]));
                evec[idx >> 5] = ev;
            }
            part[threadIdx.x >> 5] = ev;
        }
        __syncthreads();
        if (threadIdx.x == 0) {
            float z = part[0] + part[1] + part[2] + part[3] +
                      part[4] + part[5] + part[6] + part[7];
            atomicAdd(&Zb[blockIdx.x & 63], z);
        }
    }
}

// ---------------- final: out = h2(fp16) * e / Z (Z from 64 banks) ----------------
__global__ __launch_bounds__(256) void k_out(const __half* __restrict__ H,
                                             const float* __restrict__ evec,
                                             const float* __restrict__ Zb,
                                             float* __restrict__ out, int n) {
    __shared__ float sZ;
    if (threadIdx.x == 0) {
        float z = 0.f;
        #pragma unroll
        for (int i = 0; i < 64; i++) z += Zb[i];
        sZ = z;
    }
    __syncthreads();
    int idx = blockIdx.x * blockDim.x + threadIdx.x;
    int total = n * (DD / 4);
    if (idx >= total) return;
    int node = idx >> 5;
    float s = evec[node] / sZ;
    uint2 hv = ((const uint2*)H)[idx];
    const __half2* hp = (const __half2*)&hv;
    float2 h0 = __half22float2(hp[0]), h1 = __half22float2(hp[1]);
    ((float4*)out)[idx] = make_float4(h0.x * s, h0.y * s, h1.x * s, h1.y * s);
}

extern "C" void kernel_launch(void* const* d_in, const int* in_sizes, int n_in,
                              void* d_out, int out_size, void* d_ws, size_t ws_size,
                              hipStream_t stream) {
    const float* x   = (const float*)d_in[0];
    const int* eidx  = (const int*)d_in[1];
    const float* W1  = (const float*)d_in[2];
    const float* b1  = (const float*)d_in[3];
    const float* g1  = (const float*)d_in[4];
    const float* be1 = (const float*)d_in[5];
    const float* W2  = (const float*)d_in[6];
    const float* b2  = (const float*)d_in[7];
    const float* g2  = (const float*)d_in[8];
    const float* be2 = (const float*)d_in[9];
    const float* Wa  = (const float*)d_in[10];
    const float* ba  = (const float*)d_in[11];
    float* out = (float*)d_out;

    const int* srcp = eidx;
    const int* dstp = eidx + NE;

    float* bufA = (float*)d_ws;              // N*D f32 region; fp16 gather table
    float* bufB = bufA + (size_t)NN * DD;    // N*D region (evS staging / agg out fp16)
    float* bufC = bufB + (size_t)NN * DD;    // N*D region (h1 / h2 fp16)
    unsigned* ev = (unsigned*)(bufC + (size_t)NN * DD);   // NE 4B records (src)
    float* dinv = (float*)(ev + NE);         // NN
    float* evec = dinv + NN;                 // NN
    int* bcnt   = (int*)(evec + NN);         // NBUCK*NBUCK (38416, pad to 38656)
    float* sums = (float*)(bcnt + 38656);    // 2 layers x 16 banks x 256 = 8192
    float* Zb   = sums + 8192;               // 64 banks
    int* rowp   = (int*)(Zb + 64);           // NN+1 (pad 64)

    __half* hH  = (__half*)bufA;             // fp16 gather table, 12.8 MB
    unsigned* evS = (unsigned*)bufB;         // NBUCK*NBUCK*SUBCAP*4 B = 9.8 MB
    __half* hAgg = (__half*)bufB;            // fp16 agg output (evS consumed before)
    __half* hRes = (__half*)bufC;            // fp16 h1, then h2 in-place

    float* sumsL1 = sums;
    float* sumsL2 = sums + 4096;

    // ---- CSR build: 2 kernels, NO memset (binA block 0 zeroes sums/Zb) ----
    const int nA = (NE + TILE_A - 1) / TILE_A;       // 196
    k_binA<<<nA, 256, 0, stream>>>(srcp, dstp, bcnt, evS, sums, NE);
    k_binB<<<NBUCK, 256, 0, stream>>>(evS, bcnt, ev, rowp, dinv, NN);

    int agg_grid  = (NN + 15) / 16;                  // 3125
    int ew_grid   = (NN * (DD / 4) + 255) / 256;     // 6250

    // ---- layer 1 (GEMM from x fp32; table scaled by dinv) ----
    k_gemm<<<GEMM_GRID, 256, 0, stream>>>(x, nullptr, nullptr, nullptr, nullptr,
                                          nullptr, nullptr, dinv, W1, hH, NN);
    k_agg<<<agg_grid, 256, 0, stream>>>(hH, rowp, ev, dinv, b1, hAgg, sumsL1, NN);

    // ---- layer 2 (BN1+ReLU+residual fused into GEMM2 staging; h1 fp16 -> bufC) --
    k_gemm<<<GEMM_GRID, 256, 0, stream>>>(nullptr, hAgg, x, sumsL1, g1, be1,
                                          hRes, dinv, W2, hH, NN);
    k_agg<<<agg_grid, 256, 0, stream>>>(hH, rowp, ev, dinv, b2, hAgg, sumsL2, NN);
    k_bn<<<ew_grid, 256, 0, stream>>>(hAgg, hRes, sumsL2, g2, be2, Wa, ba,
                                      hRes, evec, Zb, NN);   // in-place res ok

    // ---- output ----
    k_out<<<ew_grid, 256, 0, stream>>>(hRes, evec, Zb, out, NN);
}